// Round 1
// baseline (604.303 us; speedup 1.0000x reference)
//
#include <hip/hip_runtime.h>
#include <math.h>

#define N_NODES 60
#define N_EDGES 1800
#define N_ETOT  1860
#define SLOPE   0.2f

// ---------------------------------------------------------------------------
// GNN branch: single block. Deterministic (CSR built by per-node scan, fixed
// summation order). Produces gcontrib[512] = fc1_b + g @ fc1_w[0:960,:].
// ---------------------------------------------------------------------------
__device__ __forceinline__ void block_reduce_sum(float v, float* red, float* out) {
    int tid = threadIdx.x;
    red[tid] = v;
    __syncthreads();
    for (int st = 128; st > 0; st >>= 1) {
        if (tid < st) red[tid] += red[tid + st];
        __syncthreads();
    }
    *out = red[0];
    __syncthreads();
}

__device__ void gat_layer(const float* x_in, int in_dim, int out_dim,
                          const float* W, const float* a_src, const float* a_dst,
                          const float* We, const float* a_edge, const float* bias,
                          float* xl, float* as_, float* ad_,
                          const float* ea, const int* srcs, const int* dsts,
                          const int* off, const int* csr,
                          float* alpha, float* exv, float* den_, float* outb) {
    const int tid = threadIdx.x, nt = blockDim.x;
    // xl = x @ W
    for (int idx = tid; idx < N_NODES * out_dim; idx += nt) {
        int i = idx / out_dim, j = idx % out_dim;
        float s = 0.f;
        for (int k = 0; k < in_dim; ++k) s += x_in[i * in_dim + k] * W[k * out_dim + j];
        xl[idx] = s;
    }
    __syncthreads();
    for (int i = tid; i < N_NODES; i += nt) {
        float s = 0.f, d = 0.f;
        for (int j = 0; j < out_dim; ++j) {
            s += xl[i * out_dim + j] * a_src[j];
            d += xl[i * out_dim + j] * a_dst[j];
        }
        as_[i] = s; ad_[i] = d;
    }
    float ecoef = 0.f;
    for (int j = 0; j < out_dim; ++j) ecoef += We[j] * a_edge[j];
    __syncthreads();
    for (int e = tid; e < N_ETOT; e += nt) {
        float a = as_[srcs[e]] + ad_[dsts[e]] + ea[e] * ecoef;
        alpha[e] = (a >= 0.f) ? a : SLOPE * a;
    }
    __syncthreads();
    // per-dst softmax (max then exp-sum), deterministic CSR order
    for (int d = tid; d < N_NODES; d += nt) {
        float m = -INFINITY;
        for (int k = off[d]; k < off[d + 1]; ++k) m = fmaxf(m, alpha[csr[k]]);
        float den = 0.f;
        for (int k = off[d]; k < off[d + 1]; ++k) {
            int e = csr[k];
            float ex = expf(alpha[e] - m);
            exv[e] = ex;
            den += ex;
        }
        den_[d] = den;
    }
    __syncthreads();
    // out[d][j] = sum_e w_e * xl[src[e]][j] + bias[j]
    for (int idx = tid; idx < N_NODES * out_dim; idx += nt) {
        int d = idx / out_dim, j = idx % out_dim;
        float s = 0.f;
        for (int k = off[d]; k < off[d + 1]; ++k) {
            int e = csr[k];
            s += exv[e] * xl[srcs[e] * out_dim + j];
        }
        outb[idx] = s / den_[d] + bias[j];
    }
    __syncthreads();
}

__device__ void bn_relu(const float* v, float* dst, int n, float* red) {
    const int tid = threadIdx.x, nt = blockDim.x;
    float s = 0.f;
    for (int i = tid; i < n; i += nt) s += v[i];
    float tot;
    block_reduce_sum(s, red, &tot);
    float avg = tot / n;
    float s2 = 0.f;
    for (int i = tid; i < n; i += nt) { float d = v[i] - avg; s2 += d * d; }
    block_reduce_sum(s2, red, &tot);
    float stdv = sqrtf(tot / n);
    for (int i = tid; i < n; i += nt) dst[i] = fmaxf((v[i] - avg) / stdv, 0.f);
    __syncthreads();
}

__global__ void __launch_bounds__(256) gnn_kernel(
    const float* __restrict__ node_fea, const float* __restrict__ edge_fea,
    const int* __restrict__ eidx,
    const float* g1w, const float* g1as, const float* g1ad,
    const float* g1we, const float* g1ae, const float* g1b,
    const float* g2w, const float* g2as, const float* g2ad,
    const float* g2we, const float* g2ae, const float* g2b,
    const float* __restrict__ fc1w, const float* __restrict__ fc1b,
    float* __restrict__ gcontrib) {
    __shared__ float x_in[N_NODES * 16];
    __shared__ float xl[N_NODES * 16];
    __shared__ float outb[N_NODES * 16];
    __shared__ float as_[N_NODES], ad_[N_NODES], den_[N_NODES];
    __shared__ float ea[N_ETOT], alpha[N_ETOT], exv[N_ETOT];
    __shared__ int srcs[N_ETOT], dsts[N_ETOT], csr[N_ETOT];
    __shared__ int cnt[N_NODES], off[N_NODES + 1];
    __shared__ float red[256];

    const int tid = threadIdx.x, nt = blockDim.x;
    // mean of edge features
    float s = 0.f;
    for (int e = tid; e < N_EDGES; e += nt) s += edge_fea[e];
    float tot;
    block_reduce_sum(s, red, &tot);
    float emean = tot / N_EDGES;
    // self-loop-augmented edge list
    for (int e = tid; e < N_ETOT; e += nt) {
        if (e < N_EDGES) {
            ea[e] = edge_fea[e];
            srcs[e] = eidx[e];
            dsts[e] = eidx[N_EDGES + e];
        } else {
            ea[e] = emean;
            srcs[e] = e - N_EDGES;
            dsts[e] = e - N_EDGES;
        }
    }
    if (tid < N_NODES) x_in[tid] = node_fea[tid];
    __syncthreads();
    // deterministic CSR by dst
    if (tid < N_NODES) {
        int c = 0;
        for (int e = 0; e < N_ETOT; ++e) c += (dsts[e] == tid);
        cnt[tid] = c;
    }
    __syncthreads();
    if (tid == 0) {
        off[0] = 0;
        for (int d = 0; d < N_NODES; ++d) off[d + 1] = off[d] + cnt[d];
    }
    __syncthreads();
    if (tid < N_NODES) {
        int k = off[tid];
        for (int e = 0; e < N_ETOT; ++e)
            if (dsts[e] == tid) csr[k++] = e;
    }
    __syncthreads();

    gat_layer(x_in, 1, 6, g1w, g1as, g1ad, g1we, g1ae, g1b,
              xl, as_, ad_, ea, srcs, dsts, off, csr, alpha, exv, den_, outb);
    bn_relu(outb, x_in, N_NODES * 6, red);
    gat_layer(x_in, 6, 16, g2w, g2as, g2ad, g2we, g2ae, g2b,
              xl, as_, ad_, ea, srcs, dsts, off, csr, alpha, exv, den_, outb);
    bn_relu(outb, x_in, N_NODES * 16, red);   // x_in[0..959] == g

    // gcontrib[j] = fc1_b[j] + sum_k g[k] * fc1_w[k,j]
    for (int j = tid; j < 512; j += nt) {
        float acc = fc1b[j];
        for (int k = 0; k < 960; ++k) acc += x_in[k] * fc1w[(size_t)k * 512 + j];
        gcontrib[j] = acc;
    }
}

// ---------------------------------------------------------------------------
// CNN branch: fused conv1+relu+pool + conv2+relu+pool per image.
// relu(maxpool(x)) == maxpool(relu(x)) since relu is monotone.
// ---------------------------------------------------------------------------
__global__ void __launch_bounds__(256) conv_kernel(
    const float* __restrict__ pic,
    const float* __restrict__ w1, const float* __restrict__ b1,
    const float* __restrict__ w2, const float* __restrict__ b2,
    float* __restrict__ p) {
    __shared__ float simg[3 * 32 * 32];
    __shared__ float sw1[450], sb1[6];
    __shared__ float sw2[2400], sb2[16];
    __shared__ float c1[6 * 14 * 14];

    const int b = blockIdx.x, tid = threadIdx.x;
    const float* img = pic + (size_t)b * 3072;
    for (int i = tid; i < 3072; i += 256) simg[i] = img[i];
    for (int i = tid; i < 450; i += 256) sw1[i] = w1[i];
    if (tid < 6) sb1[tid] = b1[tid];
    for (int i = tid; i < 2400; i += 256) sw2[i] = w2[i];
    if (tid < 16) sb2[tid] = b2[tid];
    __syncthreads();

    // conv1 [3,32,32] -> [6,28,28] -> relu -> pool -> [6,14,14]
    for (int o = tid; o < 6 * 14 * 14; o += 256) {
        int oc = o / 196, r = o % 196, py = r / 14, px = r % 14;
        float mx = -INFINITY;
        for (int dy = 0; dy < 2; ++dy)
            for (int dx = 0; dx < 2; ++dx) {
                int y0 = 2 * py + dy, x0 = 2 * px + dx;
                float acc = sb1[oc];
                for (int ic = 0; ic < 3; ++ic) {
                    const float* ip = &simg[ic * 1024 + y0 * 32 + x0];
                    const float* wp = &sw1[oc * 75 + ic * 25];
#pragma unroll
                    for (int ky = 0; ky < 5; ++ky)
#pragma unroll
                        for (int kx = 0; kx < 5; ++kx)
                            acc += ip[ky * 32 + kx] * wp[ky * 5 + kx];
                }
                mx = fmaxf(mx, acc);
            }
        c1[o] = fmaxf(mx, 0.f);
    }
    __syncthreads();

    // conv2 [6,14,14] -> [16,10,10] -> relu -> pool -> [16,5,5]
    for (int o = tid; o < 400; o += 256) {
        int oc = o / 25, r = o % 25, py = r / 5, px = r % 5;
        float mx = -INFINITY;
        for (int dy = 0; dy < 2; ++dy)
            for (int dx = 0; dx < 2; ++dx) {
                int y0 = 2 * py + dy, x0 = 2 * px + dx;
                float acc = sb2[oc];
                for (int ic = 0; ic < 6; ++ic) {
                    const float* ip = &c1[ic * 196 + y0 * 14 + x0];
                    const float* wp = &sw2[oc * 150 + ic * 25];
#pragma unroll
                    for (int ky = 0; ky < 5; ++ky)
#pragma unroll
                        for (int kx = 0; kx < 5; ++kx)
                            acc += ip[ky * 14 + kx] * wp[ky * 5 + kx];
                }
                mx = fmaxf(mx, acc);
            }
        p[(size_t)b * 400 + o] = fmaxf(mx, 0.f);
    }
}

// ---------------------------------------------------------------------------
// FC1: h[b,j] = relu(gcontrib[j] + sum_k p[b,k]*w2[k,j]), w2 = fc1_w[960:,:]
// ---------------------------------------------------------------------------
#define FC1_ROWS 8
__global__ void __launch_bounds__(256) fc1_kernel(
    const float* __restrict__ p, const float* __restrict__ w,
    const float* __restrict__ gcontrib, float* __restrict__ h) {
    __shared__ float sp[FC1_ROWS * 400];
    const int tid = threadIdx.x;
    const size_t r0 = (size_t)blockIdx.x * FC1_ROWS;
    for (int i = tid; i < FC1_ROWS * 400; i += 256) sp[i] = p[r0 * 400 + i];
    __syncthreads();
    const int c0 = tid, c1 = tid + 256;
    float acc[FC1_ROWS][2];
#pragma unroll
    for (int r = 0; r < FC1_ROWS; ++r) { acc[r][0] = 0.f; acc[r][1] = 0.f; }
    for (int k = 0; k < 400; ++k) {
        float w0 = w[(size_t)k * 512 + c0];
        float w1v = w[(size_t)k * 512 + c1];
#pragma unroll
        for (int r = 0; r < FC1_ROWS; ++r) {
            float pv = sp[r * 400 + k];
            acc[r][0] += pv * w0;
            acc[r][1] += pv * w1v;
        }
    }
    float g0 = gcontrib[c0], g1 = gcontrib[c1];
#pragma unroll
    for (int r = 0; r < FC1_ROWS; ++r) {
        h[(r0 + r) * 512 + c0] = fmaxf(acc[r][0] + g0, 0.f);
        h[(r0 + r) * 512 + c1] = fmaxf(acc[r][1] + g1, 0.f);
    }
}

// ---------------------------------------------------------------------------
// FC2: out[b,j] = tanh(sum_k h[b,k]*fc2_w[k,j] + fc2_b[j]); one wave per row
// ---------------------------------------------------------------------------
__global__ void __launch_bounds__(256) fc2_kernel(
    const float* __restrict__ h, const float* __restrict__ w,
    const float* __restrict__ b, float* __restrict__ out) {
    const int wave = threadIdx.x >> 6, lane = threadIdx.x & 63;
    const size_t row = (size_t)blockIdx.x * 4 + wave;
    const float* hr = h + row * 512;
    float partial[10];
#pragma unroll
    for (int j = 0; j < 10; ++j) partial[j] = 0.f;
    for (int k = lane; k < 512; k += 64) {
        float hv = hr[k];
        const float* wr = w + (size_t)k * 10;
#pragma unroll
        for (int j = 0; j < 10; ++j) partial[j] += hv * wr[j];
    }
#pragma unroll
    for (int j = 0; j < 10; ++j) {
        float v = partial[j];
        for (int sft = 32; sft > 0; sft >>= 1) v += __shfl_xor(v, sft, 64);
        partial[j] = v;
    }
    if (lane == 0) {
#pragma unroll
        for (int j = 0; j < 10; ++j)
            out[row * 10 + j] = tanhf(partial[j] + b[j]);
    }
}

extern "C" void kernel_launch(void* const* d_in, const int* in_sizes, int n_in,
                              void* d_out, int out_size, void* d_ws, size_t ws_size,
                              hipStream_t stream) {
    const float* node_fea = (const float*)d_in[0];
    const float* edge_fea = (const float*)d_in[1];
    const float* pic      = (const float*)d_in[2];
    const float* c1w = (const float*)d_in[3];
    const float* c1b = (const float*)d_in[4];
    const float* c2w = (const float*)d_in[5];
    const float* c2b = (const float*)d_in[6];
    const float* g1w  = (const float*)d_in[7];
    const float* g1as = (const float*)d_in[8];
    const float* g1ad = (const float*)d_in[9];
    const float* g1we = (const float*)d_in[10];
    const float* g1ae = (const float*)d_in[11];
    const float* g1b  = (const float*)d_in[12];
    const float* g2w  = (const float*)d_in[13];
    const float* g2as = (const float*)d_in[14];
    const float* g2ad = (const float*)d_in[15];
    const float* g2we = (const float*)d_in[16];
    const float* g2ae = (const float*)d_in[17];
    const float* g2b  = (const float*)d_in[18];
    const float* fc1w = (const float*)d_in[19];
    const float* fc1b = (const float*)d_in[20];
    const float* fc2w = (const float*)d_in[21];
    const float* fc2b = (const float*)d_in[22];
    const int*   eidx = (const int*)d_in[23];
    float* out = (float*)d_out;

    char* ws = (char*)d_ws;
    float* gcontrib = (float*)ws;                                   // 512 f
    float* p = (float*)(ws + 2048);                                 // 8192*400 f
    float* h = (float*)(ws + 2048 + (size_t)8192 * 400 * 4);        // 8192*512 f

    hipLaunchKernelGGL(gnn_kernel, dim3(1), dim3(256), 0, stream,
                       node_fea, edge_fea, eidx,
                       g1w, g1as, g1ad, g1we, g1ae, g1b,
                       g2w, g2as, g2ad, g2we, g2ae, g2b,
                       fc1w, fc1b, gcontrib);
    hipLaunchKernelGGL(conv_kernel, dim3(8192), dim3(256), 0, stream,
                       pic, c1w, c1b, c2w, c2b, p);
    hipLaunchKernelGGL(fc1_kernel, dim3(8192 / FC1_ROWS), dim3(256), 0, stream,
                       p, fc1w + (size_t)960 * 512, gcontrib, h);
    hipLaunchKernelGGL(fc2_kernel, dim3(8192 / 4), dim3(256), 0, stream,
                       h, fc2w, fc2b, out);
}

// Round 2
// 490.716 us; speedup vs baseline: 1.2315x; 1.2315x over previous
//
#include <hip/hip_runtime.h>
#include <math.h>

#define N_NODES 60
#define N_EDGES 1800
#define N_ETOT  1860
#define SLOPE   0.2f

// ---------------- LDS union: conv path vs gnn path (block 0) ----------------
#define SROW 36              // simg padded row stride (floats)
#define SCH  (32 * SROW)     // 1152
#define CROW 15              // c1 padded row stride
#define CCH  (14 * CROW)     // 210

struct ConvS {
    float simg[3 * SCH];     // 3456
    float sw1[450];
    float sb1[8];
    float sw2[2400];
    float sb2[16];
    float c1[6 * CCH];       // 1260
};
struct GnnS {
    float ea[N_ETOT];
    float alpha[N_ETOT];     // becomes exv in-place
    float x_in[960];
    float xl[960];
    float outb[960];
    float as_[N_NODES], ad_[N_NODES], den_[N_NODES];
    float red[256];
    unsigned char srcs[N_ETOT], dsts[N_ETOT];
    unsigned short csr[N_ETOT];
    int cnt[N_NODES], off[N_NODES + 4];
};
union SMem { ConvS c; GnnS g; };

__device__ __forceinline__ void block_reduce_sum(float v, float* red, float* out) {
    int tid = threadIdx.x;
    red[tid] = v;
    __syncthreads();
    for (int st = 128; st > 0; st >>= 1) {
        if (tid < st) red[tid] += red[tid + st];
        __syncthreads();
    }
    *out = red[0];
    __syncthreads();
}

__device__ void gat_layer(GnnS& S, const float* x_in, int in_dim, int out_dim,
                          const float* W, const float* a_src, const float* a_dst,
                          const float* We, const float* a_edge, const float* bias,
                          float* xl, float* outb) {
    const int tid = threadIdx.x, nt = blockDim.x;
    for (int idx = tid; idx < N_NODES * out_dim; idx += nt) {
        int i = idx / out_dim, j = idx % out_dim;
        float s = 0.f;
        for (int k = 0; k < in_dim; ++k) s += x_in[i * in_dim + k] * W[k * out_dim + j];
        xl[idx] = s;
    }
    __syncthreads();
    for (int i = tid; i < N_NODES; i += nt) {
        float s = 0.f, d = 0.f;
        for (int j = 0; j < out_dim; ++j) {
            s += xl[i * out_dim + j] * a_src[j];
            d += xl[i * out_dim + j] * a_dst[j];
        }
        S.as_[i] = s; S.ad_[i] = d;
    }
    float ecoef = 0.f;
    for (int j = 0; j < out_dim; ++j) ecoef += We[j] * a_edge[j];
    __syncthreads();
    for (int e = tid; e < N_ETOT; e += nt) {
        float a = S.as_[S.srcs[e]] + S.ad_[S.dsts[e]] + S.ea[e] * ecoef;
        S.alpha[e] = (a >= 0.f) ? a : SLOPE * a;
    }
    __syncthreads();
    // per-dst softmax over CSR (deterministic order); exp written in place
    for (int d = tid; d < N_NODES; d += nt) {
        float m = -INFINITY;
        for (int k = S.off[d]; k < S.off[d + 1]; ++k) m = fmaxf(m, S.alpha[S.csr[k]]);
        float den = 0.f;
        for (int k = S.off[d]; k < S.off[d + 1]; ++k) {
            int e = S.csr[k];
            float ex = expf(S.alpha[e] - m);
            S.alpha[e] = ex;
            den += ex;
        }
        S.den_[d] = den;
    }
    __syncthreads();
    for (int idx = tid; idx < N_NODES * out_dim; idx += nt) {
        int d = idx / out_dim, j = idx % out_dim;
        float s = 0.f;
        for (int k = S.off[d]; k < S.off[d + 1]; ++k) {
            int e = S.csr[k];
            s += S.alpha[e] * xl[(int)S.srcs[e] * out_dim + j];
        }
        outb[idx] = s / S.den_[d] + bias[j];
    }
    __syncthreads();
}

__device__ void bn_relu(GnnS& S, const float* v, float* dst, int n) {
    const int tid = threadIdx.x, nt = blockDim.x;
    float s = 0.f;
    for (int i = tid; i < n; i += nt) s += v[i];
    float tot;
    block_reduce_sum(s, S.red, &tot);
    float avg = tot / n;
    float s2 = 0.f;
    for (int i = tid; i < n; i += nt) { float d = v[i] - avg; s2 += d * d; }
    block_reduce_sum(s2, S.red, &tot);
    float stdv = sqrtf(tot / n);
    for (int i = tid; i < n; i += nt) dst[i] = fmaxf((v[i] - avg) / stdv, 0.f);
    __syncthreads();
}

__device__ void gnn_path(GnnS& S,
    const float* node_fea, const float* edge_fea, const int* eidx,
    const float* g1w, const float* g1as, const float* g1ad,
    const float* g1we, const float* g1ae, const float* g1b,
    const float* g2w, const float* g2as, const float* g2ad,
    const float* g2we, const float* g2ae, const float* g2b,
    const float* fc1w, const float* fc1b, float* gcontrib) {
    const int tid = threadIdx.x, nt = blockDim.x;
    float s = 0.f;
    for (int e = tid; e < N_EDGES; e += nt) s += edge_fea[e];
    float tot;
    block_reduce_sum(s, S.red, &tot);
    float emean = tot / N_EDGES;
    for (int e = tid; e < N_ETOT; e += nt) {
        if (e < N_EDGES) {
            S.ea[e] = edge_fea[e];
            S.srcs[e] = (unsigned char)eidx[e];
            S.dsts[e] = (unsigned char)eidx[N_EDGES + e];
        } else {
            S.ea[e] = emean;
            S.srcs[e] = (unsigned char)(e - N_EDGES);
            S.dsts[e] = (unsigned char)(e - N_EDGES);
        }
    }
    if (tid < N_NODES) S.x_in[tid] = node_fea[tid];
    __syncthreads();
    if (tid < N_NODES) {
        int c = 0;
        for (int e = 0; e < N_ETOT; ++e) c += (S.dsts[e] == tid);
        S.cnt[tid] = c;
    }
    __syncthreads();
    if (tid == 0) {
        S.off[0] = 0;
        for (int d = 0; d < N_NODES; ++d) S.off[d + 1] = S.off[d] + S.cnt[d];
    }
    __syncthreads();
    if (tid < N_NODES) {
        int k = S.off[tid];
        for (int e = 0; e < N_ETOT; ++e)
            if (S.dsts[e] == tid) S.csr[k++] = (unsigned short)e;
    }
    __syncthreads();

    gat_layer(S, S.x_in, 1, 6, g1w, g1as, g1ad, g1we, g1ae, g1b, S.xl, S.outb);
    bn_relu(S, S.outb, S.x_in, N_NODES * 6);
    gat_layer(S, S.x_in, 6, 16, g2w, g2as, g2ad, g2we, g2ae, g2b, S.xl, S.outb);
    bn_relu(S, S.outb, S.x_in, N_NODES * 16);   // x_in[0..959] == g

    for (int j = tid; j < 512; j += nt) {
        float acc = fc1b[j];
#pragma unroll 4
        for (int k = 0; k < 960; ++k) acc += S.x_in[k] * fc1w[(size_t)k * 512 + j];
        gcontrib[j] = acc;
    }
}

// ---------------------------------------------------------------------------
// conv path: fused conv1+relu+pool + conv2+relu+pool, register-blocked 2x2
// pooled pairs. relu(maxpool(x)) == maxpool(relu(x)).
// ---------------------------------------------------------------------------
__device__ void conv_path(ConvS& C, int b,
                          const float* __restrict__ pic,
                          const float* __restrict__ w1, const float* __restrict__ b1,
                          const float* __restrict__ w2, const float* __restrict__ b2,
                          float* __restrict__ p) {
    const int tid = threadIdx.x;
    const float* img = pic + (size_t)b * 3072;
    for (int i = tid; i < 3072; i += 256) {
        int ic = i >> 10, rem = i & 1023, y = rem >> 5, x = rem & 31;
        C.simg[ic * SCH + y * SROW + x] = img[i];
    }
    for (int i = tid; i < 450; i += 256) C.sw1[i] = w1[i];
    if (tid < 6) C.sb1[tid] = b1[tid];
    for (int i = tid; i < 2400; i += 256) C.sw2[i] = w2[i];
    if (tid < 16) C.sb2[tid] = b2[tid];
    __syncthreads();

    // conv1: items = (oc,py,q): 6*14*7 = 588; each computes pooled (py,2q),(py,2q+1)
    for (int it = tid; it < 588; it += 256) {
        int oc = it / 98, r = it % 98, py = r / 7, q = r % 7;
        int y0 = 2 * py, x0 = 4 * q;
        float bias = C.sb1[oc];
        float acc[2][4];
#pragma unroll
        for (int dy = 0; dy < 2; ++dy)
#pragma unroll
            for (int xi = 0; xi < 4; ++xi) acc[dy][xi] = bias;
        for (int ic = 0; ic < 3; ++ic) {
            float wr[25];
            const float* wp = &C.sw1[oc * 75 + ic * 25];
#pragma unroll
            for (int t = 0; t < 25; ++t) wr[t] = wp[t];
            const int base = ic * SCH + y0 * SROW + x0;
#pragma unroll
            for (int i = 0; i < 6; ++i) {
                const float4* rp = (const float4*)&C.simg[base + i * SROW];
                float4 va = rp[0], vb = rp[1];
                float row[8] = {va.x, va.y, va.z, va.w, vb.x, vb.y, vb.z, vb.w};
#pragma unroll
                for (int dy = 0; dy < 2; ++dy) {
                    int ky = i - dy;
                    if (ky >= 0 && ky < 5) {
#pragma unroll
                        for (int xi = 0; xi < 4; ++xi) {
                            float s = 0.f;
#pragma unroll
                            for (int kx = 0; kx < 5; ++kx)
                                s += row[xi + kx] * wr[ky * 5 + kx];
                            acc[dy][xi] += s;
                        }
                    }
                }
            }
        }
#pragma unroll
        for (int sx = 0; sx < 2; ++sx) {
            float mx = fmaxf(fmaxf(acc[0][2 * sx], acc[0][2 * sx + 1]),
                             fmaxf(acc[1][2 * sx], acc[1][2 * sx + 1]));
            C.c1[oc * CCH + py * CROW + 2 * q + sx] = fmaxf(mx, 0.f);
        }
    }
    __syncthreads();

    // conv2: items = (oc,py,g): 16*5*3 = 240; g<2 -> pooled px {2g,2g+1}; g==2 -> px 4
    if (tid < 240) {
        int oc = tid / 15, r = tid % 15, py = r / 3, g = r % 3;
        int y0 = 2 * py, x0 = 4 * g;
        float bias = C.sb2[oc];
        float acc[2][4];
#pragma unroll
        for (int dy = 0; dy < 2; ++dy)
#pragma unroll
            for (int xi = 0; xi < 4; ++xi) acc[dy][xi] = bias;
        for (int ic = 0; ic < 6; ++ic) {
            float wr[25];
            const float* wp = &C.sw2[oc * 150 + ic * 25];
#pragma unroll
            for (int t = 0; t < 25; ++t) wr[t] = wp[t];
            const int base = ic * CCH + y0 * CROW + x0;
#pragma unroll
            for (int i = 0; i < 6; ++i) {
                float row[8];
#pragma unroll
                for (int j = 0; j < 8; ++j) row[j] = C.c1[base + i * CROW + j];
#pragma unroll
                for (int dy = 0; dy < 2; ++dy) {
                    int ky = i - dy;
                    if (ky >= 0 && ky < 5) {
#pragma unroll
                        for (int xi = 0; xi < 4; ++xi) {
                            float s = 0.f;
#pragma unroll
                            for (int kx = 0; kx < 5; ++kx)
                                s += row[xi + kx] * wr[ky * 5 + kx];
                            acc[dy][xi] += s;
                        }
                    }
                }
            }
        }
        int nsx = (g < 2) ? 2 : 1;
        for (int sx = 0; sx < nsx; ++sx) {
            float mx = fmaxf(fmaxf(acc[0][2 * sx], acc[0][2 * sx + 1]),
                             fmaxf(acc[1][2 * sx], acc[1][2 * sx + 1]));
            p[(size_t)b * 400 + oc * 25 + py * 5 + 2 * g + sx] = fmaxf(mx, 0.f);
        }
    }
}

__global__ void __launch_bounds__(256, 4) fused_kernel(
    const float* __restrict__ node_fea, const float* __restrict__ edge_fea,
    const int* __restrict__ eidx,
    const float* g1w, const float* g1as, const float* g1ad,
    const float* g1we, const float* g1ae, const float* g1b,
    const float* g2w, const float* g2as, const float* g2ad,
    const float* g2we, const float* g2ae, const float* g2b,
    const float* __restrict__ fc1w, const float* __restrict__ fc1b,
    float* __restrict__ gcontrib,
    const float* __restrict__ pic,
    const float* __restrict__ c1w, const float* __restrict__ c1b,
    const float* __restrict__ c2w, const float* __restrict__ c2b,
    float* __restrict__ p) {
    __shared__ SMem u;
    if (blockIdx.x == 0) {
        gnn_path(u.g, node_fea, edge_fea, eidx,
                 g1w, g1as, g1ad, g1we, g1ae, g1b,
                 g2w, g2as, g2ad, g2we, g2ae, g2b,
                 fc1w, fc1b, gcontrib);
    } else {
        conv_path(u.c, blockIdx.x - 1, pic, c1w, c1b, c2w, c2b, p);
    }
}

// ---------------------------------------------------------------------------
// FC1: h[b,j] = relu(gcontrib[j] + sum_k p[b,k]*w2[k,j]); w2 = fc1_w[960:,:]
// ---------------------------------------------------------------------------
#define FC1_ROWS 16
__global__ void __launch_bounds__(256) fc1_kernel(
    const float* __restrict__ p, const float* __restrict__ w,
    const float* __restrict__ gcontrib, float* __restrict__ h) {
    __shared__ float sp[FC1_ROWS * 400];
    const int tid = threadIdx.x;
    const size_t r0 = (size_t)blockIdx.x * FC1_ROWS;
    for (int i = tid; i < FC1_ROWS * 400; i += 256) sp[i] = p[r0 * 400 + i];
    __syncthreads();
    const int c0 = tid, c1 = tid + 256;
    float acc[FC1_ROWS][2];
#pragma unroll
    for (int r = 0; r < FC1_ROWS; ++r) { acc[r][0] = 0.f; acc[r][1] = 0.f; }
    for (int k = 0; k < 400; k += 4) {
        float wa0 = w[(size_t)(k + 0) * 512 + c0], wa1 = w[(size_t)(k + 0) * 512 + c1];
        float wb0 = w[(size_t)(k + 1) * 512 + c0], wb1 = w[(size_t)(k + 1) * 512 + c1];
        float wc0 = w[(size_t)(k + 2) * 512 + c0], wc1 = w[(size_t)(k + 2) * 512 + c1];
        float wd0 = w[(size_t)(k + 3) * 512 + c0], wd1 = w[(size_t)(k + 3) * 512 + c1];
#pragma unroll
        for (int r = 0; r < FC1_ROWS; ++r) {
            float4 pv = *(const float4*)&sp[r * 400 + k];
            acc[r][0] += pv.x * wa0 + pv.y * wb0 + pv.z * wc0 + pv.w * wd0;
            acc[r][1] += pv.x * wa1 + pv.y * wb1 + pv.z * wc1 + pv.w * wd1;
        }
    }
    float g0 = gcontrib[c0], g1 = gcontrib[c1];
#pragma unroll
    for (int r = 0; r < FC1_ROWS; ++r) {
        h[(r0 + r) * 512 + c0] = fmaxf(acc[r][0] + g0, 0.f);
        h[(r0 + r) * 512 + c1] = fmaxf(acc[r][1] + g1, 0.f);
    }
}

// ---------------------------------------------------------------------------
// FC2: out[b,j] = tanh(sum_k h[b,k]*fc2_w[k,j] + fc2_b[j]); one wave per row
// ---------------------------------------------------------------------------
__global__ void __launch_bounds__(256) fc2_kernel(
    const float* __restrict__ h, const float* __restrict__ w,
    const float* __restrict__ b, float* __restrict__ out) {
    const int wave = threadIdx.x >> 6, lane = threadIdx.x & 63;
    const size_t row = (size_t)blockIdx.x * 4 + wave;
    const float* hr = h + row * 512;
    float partial[10];
#pragma unroll
    for (int j = 0; j < 10; ++j) partial[j] = 0.f;
    for (int k = lane; k < 512; k += 64) {
        float hv = hr[k];
        const float* wr = w + (size_t)k * 10;
#pragma unroll
        for (int j = 0; j < 10; ++j) partial[j] += hv * wr[j];
    }
#pragma unroll
    for (int j = 0; j < 10; ++j) {
        float v = partial[j];
        for (int sft = 32; sft > 0; sft >>= 1) v += __shfl_xor(v, sft, 64);
        partial[j] = v;
    }
    if (lane == 0) {
#pragma unroll
        for (int j = 0; j < 10; ++j)
            out[row * 10 + j] = tanhf(partial[j] + b[j]);
    }
}

extern "C" void kernel_launch(void* const* d_in, const int* in_sizes, int n_in,
                              void* d_out, int out_size, void* d_ws, size_t ws_size,
                              hipStream_t stream) {
    const float* node_fea = (const float*)d_in[0];
    const float* edge_fea = (const float*)d_in[1];
    const float* pic      = (const float*)d_in[2];
    const float* c1w = (const float*)d_in[3];
    const float* c1b = (const float*)d_in[4];
    const float* c2w = (const float*)d_in[5];
    const float* c2b = (const float*)d_in[6];
    const float* g1w  = (const float*)d_in[7];
    const float* g1as = (const float*)d_in[8];
    const float* g1ad = (const float*)d_in[9];
    const float* g1we = (const float*)d_in[10];
    const float* g1ae = (const float*)d_in[11];
    const float* g1b  = (const float*)d_in[12];
    const float* g2w  = (const float*)d_in[13];
    const float* g2as = (const float*)d_in[14];
    const float* g2ad = (const float*)d_in[15];
    const float* g2we = (const float*)d_in[16];
    const float* g2ae = (const float*)d_in[17];
    const float* g2b  = (const float*)d_in[18];
    const float* fc1w = (const float*)d_in[19];
    const float* fc1b = (const float*)d_in[20];
    const float* fc2w = (const float*)d_in[21];
    const float* fc2b = (const float*)d_in[22];
    const int*   eidx = (const int*)d_in[23];
    float* out = (float*)d_out;

    char* ws = (char*)d_ws;
    float* gcontrib = (float*)ws;                                   // 512 f
    float* p = (float*)(ws + 2048);                                 // 8192*400 f
    float* h = (float*)(ws + 2048 + (size_t)8192 * 400 * 4);        // 8192*512 f

    hipLaunchKernelGGL(fused_kernel, dim3(8193), dim3(256), 0, stream,
                       node_fea, edge_fea, eidx,
                       g1w, g1as, g1ad, g1we, g1ae, g1b,
                       g2w, g2as, g2ad, g2we, g2ae, g2b,
                       fc1w, fc1b, gcontrib,
                       pic, c1w, c1b, c2w, c2b, p);
    hipLaunchKernelGGL(fc1_kernel, dim3(8192 / FC1_ROWS), dim3(256), 0, stream,
                       p, fc1w + (size_t)960 * 512, gcontrib, h);
    hipLaunchKernelGGL(fc2_kernel, dim3(8192 / 4), dim3(256), 0, stream,
                       h, fc2w, fc2b, out);
}